// Round 4
// baseline (131.060 us; speedup 1.0000x reference)
//
#include <hip/hip_runtime.h>
#include <stdint.h>
#include <stddef.h>

// BlockLinear: out[b, g*512+n] = sum_m x[b, g*512+m] * blocks[g, m, n]
// G=8, M=N=512, TOKENS=8192. fp32 in/out; compute in bf16 MFMA.
// Round 4: TLP-first. A-only LDS (32 KB dbuf), B fragments read directly
// from L2-resident bT[g], one barrier per K-tile, 2-3 blocks/CU.

typedef __attribute__((ext_vector_type(8))) short sv8;   // 8 x bf16 fragment
typedef __attribute__((ext_vector_type(4))) float fv4;   // 4 x f32 accum

__device__ __forceinline__ uint32_t f2bf(float f) {
    union { float f; uint32_t u; } v; v.f = f;
    uint32_t u = v.u;
    u += 0x7FFFu + ((u >> 16) & 1u);   // RNE
    return u >> 16;
}
__device__ __forceinline__ uint32_t pk2(float a, float b) {
    return f2bf(a) | (f2bf(b) << 16);
}

// blocksT[g][n][k] (bf16) = blocks[g][k][n] (f32)
__global__ void bl_transpose(const float* __restrict__ blocks,
                             unsigned short* __restrict__ bT) {
    __shared__ float tile[64][65];
    const int g  = blockIdx.z;
    const int k0 = blockIdx.y * 64;
    const int n0 = blockIdx.x * 64;
    const float* src = blocks + (size_t)g * 512 * 512;
    unsigned short* dst = bT + (size_t)g * 512 * 512;
    const int lane = threadIdx.x & 63;
    const int r0   = threadIdx.x >> 6;   // 0..3
    for (int r = r0; r < 64; r += 4)
        tile[r][lane] = src[(size_t)(k0 + r) * 512 + n0 + lane];
    __syncthreads();
    for (int r = r0; r < 64; r += 4)
        dst[(size_t)(n0 + r) * 512 + k0 + lane] = (unsigned short)f2bf(tile[lane][r]);
}

// Main GEMM: BM=128, BN=256, BK=64, 512 threads (8 waves, 2Mx4N grid,
// wave tile 64x64 = 4x4 fragments of 16x16x32 bf16 MFMA).
// A staged in LDS (f32->bf16 cvt at staging, XOR-swizzled, double-buffered);
// B fragments loaded directly from global (L2-resident 512 KB panel per XCD).
__global__ __launch_bounds__(512) void bl_gemm(
    const float* __restrict__ x,            // [8192][4096]
    const unsigned short* __restrict__ bT,  // [8][512 n][512 k] bf16
    float* __restrict__ out)                // [8192][4096]
{
    __shared__ __align__(16) unsigned short As[2][128 * 64];  // 32 KiB total

    const int bid = blockIdx.x;
    const int g   = bid & 7;          // group == XCD (round-robin dispatch)
    const int rem = bid >> 3;
    const int nt  = rem & 1;
    const int mt  = rem >> 1;         // 0..63

    const int tid  = threadIdx.x;
    const int lane = tid & 63;
    const int wid  = tid >> 6;        // 0..7
    const int wm   = wid >> 2;        // 0..1
    const int wn   = wid & 3;         // 0..3
    const int lr   = lane & 15;
    const int lg   = lane >> 4;

    fv4 acc[4][4];
#pragma unroll
    for (int i = 0; i < 4; ++i)
#pragma unroll
        for (int j = 0; j < 4; ++j)
            acc[i][j] = (fv4){0.f, 0.f, 0.f, 0.f};

    const float* xg = x + (size_t)(mt * 128) * 4096 + g * 512;
    // B panel base for this wave: rows (nt*256 + wn*64 + ...), k contiguous
    const unsigned short* bgn = bT + ((size_t)g * 512 + nt * 256 + wn * 64) * 512;

    // ---- A staging: thread -> rows ar0, ar0+64; k-chunk ac (8 floats) ----
    const int ac  = tid & 7;
    const int ar0 = tid >> 3;                        // 0..63
    const float* aSrc   = xg + (size_t)ar0 * 4096 + ac * 8;
    const int    aSlotB = (ac ^ (ar0 & 7)) * 16;     // swizzled 16B slot (byte)
    const int    aOff0  = ar0 * 128 + aSlotB;
    const int    aOff1  = (ar0 + 64) * 128 + aSlotB;

    // ---- A fragment read bases (row&7 == lr&7) ----
    const int aReadBase = (wm * 64 + lr) * 128;

    float4 arg_[4];   // in-flight A: rows {ar0, ar0+64} x 2 float4 each

#define ISSUE_A(kt)                                                        \
    do {                                                                   \
        const float* s0_ = aSrc + (kt) * 64;                               \
        const float* s1_ = aSrc + (size_t)64 * 4096 + (kt) * 64;           \
        arg_[0] = *(const float4*)s0_;                                     \
        arg_[1] = *(const float4*)(s0_ + 4);                               \
        arg_[2] = *(const float4*)s1_;                                     \
        arg_[3] = *(const float4*)(s1_ + 4);                               \
    } while (0)

#define WRITE_A(bufw)                                                      \
    do {                                                                   \
        uint4 w0_, w1_;                                                    \
        w0_.x = pk2(arg_[0].x, arg_[0].y); w0_.y = pk2(arg_[0].z, arg_[0].w); \
        w0_.z = pk2(arg_[1].x, arg_[1].y); w0_.w = pk2(arg_[1].z, arg_[1].w); \
        w1_.x = pk2(arg_[2].x, arg_[2].y); w1_.y = pk2(arg_[2].z, arg_[2].w); \
        w1_.z = pk2(arg_[3].x, arg_[3].y); w1_.w = pk2(arg_[3].z, arg_[3].w); \
        *(uint4*)((char*)&As[bufw][0] + aOff0) = w0_;                      \
        *(uint4*)((char*)&As[bufw][0] + aOff1) = w1_;                      \
    } while (0)

    // ---- prologue: stage tile 0 ----
    ISSUE_A(0);
    WRITE_A(0);
    __syncthreads();

    int buf = 0;
#pragma unroll 1
    for (int kt = 0; kt < 8; ++kt) {
        if (kt < 7) ISSUE_A(kt + 1);   // x loads in flight during compute

        const char* Ab = (const char*)&As[buf][0];
        // B fragments for the whole K-tile, direct from L2 (16 rows x 64B
        // per instruction across the wave -> full cache lines).
        sv8 b0[4], b1[4], a0[4], a1[4];
        const int ks0 = ((0 + lg) ^ (lr & 7)) * 16;
        const int ks1 = ((4 + lg) ^ (lr & 7)) * 16;
#pragma unroll
        for (int ni = 0; ni < 4; ++ni) {
            const unsigned short* br = bgn + (size_t)(ni * 16 + lr) * 512 + kt * 64;
            b0[ni] = *(const sv8*)(br + (0 + lg) * 8);
            b1[ni] = *(const sv8*)(br + (4 + lg) * 8);
        }
#pragma unroll
        for (int mi = 0; mi < 4; ++mi) {
            const char* p_ = Ab + aReadBase + mi * 16 * 128;
            a0[mi] = *(const sv8*)(p_ + ks0);
            a1[mi] = *(const sv8*)(p_ + ks1);
        }
        // operand order (b, a): lane&15 indexes m, q indexes n (4 consecutive)
#pragma unroll
        for (int mi = 0; mi < 4; ++mi)
#pragma unroll
            for (int ni = 0; ni < 4; ++ni) {
                acc[mi][ni] = __builtin_amdgcn_mfma_f32_16x16x32_bf16(
                    b0[ni], a0[mi], acc[mi][ni], 0, 0, 0);
                acc[mi][ni] = __builtin_amdgcn_mfma_f32_16x16x32_bf16(
                    b1[ni], a1[mi], acc[mi][ni], 0, 0, 0);
            }

        if (kt < 7) WRITE_A(buf ^ 1);  // write next tile (other buffer)
        __syncthreads();
        buf ^= 1;
    }

    // ---- epilogue: float4 stores (lane holds 4 consecutive n) ----
    float* og = out + (size_t)(mt * 128 + wm * 64) * 4096 + g * 512 + nt * 256 + wn * 64;
#pragma unroll
    for (int mi = 0; mi < 4; ++mi)
#pragma unroll
        for (int ni = 0; ni < 4; ++ni) {
            float4 v;
            v.x = acc[mi][ni][0]; v.y = acc[mi][ni][1];
            v.z = acc[mi][ni][2]; v.w = acc[mi][ni][3];
            *(float4*)(og + (size_t)(mi * 16 + lr) * 4096 + ni * 16 + lg * 4) = v;
        }

#undef ISSUE_A
#undef WRITE_A
}

// Safety net if ws is too small for the bf16 transposed blocks (4 MiB).
__global__ void bl_fallback(const float* __restrict__ x,
                            const float* __restrict__ blocks,
                            float* __restrict__ out) {
    const int o = blockIdx.x * 256 + threadIdx.x;
    const int col = o & 4095;
    const int row = o >> 12;
    const int g = col >> 9;
    const int n = col & 511;
    const float* xr = x + (size_t)row * 4096 + g * 512;
    const float* wp = blocks + (size_t)g * 512 * 512 + n;
    float s = 0.f;
    for (int m = 0; m < 512; ++m) s += xr[m] * wp[(size_t)m * 512];
    out[o] = s;
}

extern "C" void kernel_launch(void* const* d_in, const int* in_sizes, int n_in,
                              void* d_out, int out_size, void* d_ws, size_t ws_size,
                              hipStream_t stream) {
    const float* x      = (const float*)d_in[0];
    const float* blocks = (const float*)d_in[1];
    float* out          = (float*)d_out;

    const size_t need = (size_t)8 * 512 * 512 * sizeof(unsigned short); // 4 MiB
    if (ws_size >= need) {
        unsigned short* bT = (unsigned short*)d_ws;
        bl_transpose<<<dim3(8, 8, 8), 256, 0, stream>>>(blocks, bT);
        bl_gemm<<<1024, 512, 0, stream>>>(x, bT, out);
    } else {
        bl_fallback<<<(8192 * 4096) / 256, 256, 0, stream>>>(x, blocks, out);
    }
}

// Round 5
// 72.388 us; speedup vs baseline: 1.8105x; 1.8105x over previous
//
#include <hip/hip_runtime.h>
#include <stdint.h>
#include <stddef.h>

// BlockLinear: out[b, g*512+n] = sum_m x[b, g*512+m] * blocks[g, m, n]
// G=8, M=N=512, TOKENS=8192. fp32 in/out; compute in bf16 MFMA.
// Round 5: TLP via many small blocks. 4-wave blocks, BM=64 BN=256 BK=32,
// 40KB LDS -> 4 blocks/CU. Pack kernel pre-arranges B in gl_lds-linear
// order (slot = c ^ (n&3)); all LDS accesses conflict-free. Nontemporal
// out stores keep x L3-resident.

typedef __attribute__((ext_vector_type(8))) short sv8;   // 8 x bf16 fragment
typedef __attribute__((ext_vector_type(4))) float fv4;   // 4 x f32 accum

__device__ __forceinline__ uint32_t f2bf(float f) {
    union { float f; uint32_t u; } v; v.f = f;
    uint32_t u = v.u;
    u += 0x7FFFu + ((u >> 16) & 1u);   // RNE
    return u >> 16;
}
__device__ __forceinline__ uint32_t pk2(float a, float b) {
    return f2bf(a) | (f2bf(b) << 16);
}
__device__ __forceinline__ void gl_lds16(const void* g, void* lds) {
    __builtin_amdgcn_global_load_lds(
        (const __attribute__((address_space(1))) void*)g,
        (__attribute__((address_space(3))) void*)lds, 16, 0, 0);
}

// bTgl[g][kt][n*4+slot] : 16B unit = bf16(blocks[g][kt*32 + c*8 + e][n]),
// e=0..7, c = slot ^ (n&3).  8 g x 16 kt x 2048 units x 16B = 4 MiB.
__global__ void bl_pack(const float* __restrict__ blocks,
                        unsigned short* __restrict__ bTgl) {
    __shared__ float tile[64][65];
    const int g  = blockIdx.z;
    const int mt = blockIdx.y;           // 64 m-rows -> kt = mt*2 + {0,1}
    const int n0 = blockIdx.x * 64;
    const float* src = blocks + (size_t)g * 512 * 512;
    const int lane = threadIdx.x & 63;
    const int r0   = threadIdx.x >> 6;   // 0..3
    for (int r = r0; r < 64; r += 4)
        tile[r][lane] = src[(size_t)(mt * 64 + r) * 512 + n0 + lane];
    __syncthreads();
    const int t    = threadIdx.x;        // 0..255
    const int nl   = t >> 2;
    const int slot = t & 3;
    const int c    = slot ^ (nl & 3);    // n0 is a multiple of 64
#pragma unroll
    for (int ktl = 0; ktl < 2; ++ktl) {
        const int mb = ktl * 32 + c * 8;
        uint4 w;
        w.x = pk2(tile[mb + 0][nl], tile[mb + 1][nl]);
        w.y = pk2(tile[mb + 2][nl], tile[mb + 3][nl]);
        w.z = pk2(tile[mb + 4][nl], tile[mb + 5][nl]);
        w.w = pk2(tile[mb + 6][nl], tile[mb + 7][nl]);
        const size_t u = ((size_t)(g * 16 + mt * 2 + ktl)) * 2048 + (n0 + nl) * 4 + slot;
        *(uint4*)(bTgl + u * 8) = w;
    }
}

// Main GEMM: BM=64, BN=256, BK=32, 256 threads (4 waves, 1Mx4N),
// wave tile 64x64 = 4x4 fragments of 16x16x32 bf16 MFMA (1 MFMA/frag-pair
// per K-tile since BK=32). Double-buffered LDS (40 KiB -> 4 blocks/CU).
__global__ __launch_bounds__(256, 4) void bl_gemm(
    const float* __restrict__ x,              // [8192][4096]
    const unsigned short* __restrict__ bTgl,  // packed B, see bl_pack
    float* __restrict__ out)                  // [8192][4096]
{
    __shared__ __align__(16) unsigned short As[2][64 * 32];    //  8 KiB
    __shared__ __align__(16) unsigned short Bs[2][256 * 32];   // 32 KiB

    const int bid = blockIdx.x;
    const int g   = bid & 7;          // group ~ XCD (round-robin dispatch)
    const int rem = bid >> 3;
    const int nt  = rem & 1;
    const int mt  = rem >> 1;         // 0..127

    const int tid  = threadIdx.x;
    const int lane = tid & 63;
    const int w    = tid >> 6;        // 0..3 = wn
    const int lr   = lane & 15;
    const int lg   = lane >> 4;

    fv4 acc[4][4];
#pragma unroll
    for (int i = 0; i < 4; ++i)
#pragma unroll
        for (int j = 0; j < 4; ++j)
            acc[i][j] = (fv4){0.f, 0.f, 0.f, 0.f};

    const float* xg = x + (size_t)(mt * 64) * 4096 + g * 512;

    // ---- A staging: thread -> row arow (0..63), k-chunk ac (8 floats) ----
    const int arow = tid >> 2;
    const int ac   = tid & 3;
    const float* aSrc = xg + (size_t)arow * 4096 + ac * 8;
    const int aOff = arow * 64 + ((ac ^ (arow & 3)) * 16);   // byte offset

    // ---- B staging: 4 gl_lds per wave, fully linear (packed layout) ----
    // per kt slab: 2048 units; block slice: [nt*1024, nt*1024+1024)
    const unsigned short* bKt0 =
        bTgl + ((size_t)g * 16) * 2048 * 8 + (size_t)nt * 1024 * 8 +
        (size_t)(w * 256 + lane) * 8;
    // LDS dst base per (w,p): (w*256 + p*64)*16 bytes; HW adds lane*16.

    // ---- fragment read offsets (bytes); row&3 == lr&3 everywhere ----
    const int slotOff = (lg ^ (lr & 3)) * 16;

    float4 ar0_, ar1_;   // in-flight A (8 floats)

#define ISSUE_A(kt)                                                        \
    do {                                                                   \
        const float* s_ = aSrc + (kt) * 32;                                \
        ar0_ = *(const float4*)s_;                                         \
        ar1_ = *(const float4*)(s_ + 4);                                   \
    } while (0)

#define ISSUE_B(kt, bufw)                                                  \
    do { _Pragma("unroll") for (int p = 0; p < 4; ++p)                     \
        gl_lds16(bKt0 + (size_t)(kt) * 16384 + p * 64 * 8,                 \
                 (char*)&Bs[bufw][0] + (w * 256 + p * 64) * 16);           \
    } while (0)

#define WRITE_A(bufw)                                                      \
    do {                                                                   \
        uint4 w_;                                                          \
        w_.x = pk2(ar0_.x, ar0_.y); w_.y = pk2(ar0_.z, ar0_.w);            \
        w_.z = pk2(ar1_.x, ar1_.y); w_.w = pk2(ar1_.z, ar1_.w);            \
        *(uint4*)((char*)&As[bufw][0] + aOff) = w_;                        \
    } while (0)

#define COMPUTE(rb)                                                        \
    do {                                                                   \
        sv8 a_[4], b_[4];                                                  \
        _Pragma("unroll") for (int mi = 0; mi < 4; ++mi)                   \
            a_[mi] = *(const sv8*)((const char*)&As[rb][0] +               \
                                   (mi * 16 + lr) * 64 + slotOff);         \
        _Pragma("unroll") for (int ni = 0; ni < 4; ++ni)                   \
            b_[ni] = *(const sv8*)((const char*)&Bs[rb][0] +               \
                                   (w * 64 + ni * 16 + lr) * 64 + slotOff);\
        __builtin_amdgcn_s_setprio(1);                                     \
        _Pragma("unroll") for (int mi = 0; mi < 4; ++mi)                   \
        _Pragma("unroll") for (int ni = 0; ni < 4; ++ni)                   \
            acc[mi][ni] = __builtin_amdgcn_mfma_f32_16x16x32_bf16(         \
                b_[ni], a_[mi], acc[mi][ni], 0, 0, 0);                     \
        __builtin_amdgcn_s_setprio(0);                                     \
    } while (0)

    // ---- prologue ----
    ISSUE_A(0);
    ISSUE_B(0, 0);
    WRITE_A(0);
    __syncthreads();

#pragma unroll 1
    for (int kt = 0; kt < 16; kt += 2) {
        // tile kt in buf0; stage kt+1 -> buf1
        ISSUE_A(kt + 1);
        ISSUE_B(kt + 1, 1);
        COMPUTE(0);
        WRITE_A(1);
        __syncthreads();
        // tile kt+1 in buf1; stage kt+2 -> buf0
        if (kt + 2 < 16) { ISSUE_A(kt + 2); ISSUE_B(kt + 2, 0); }
        COMPUTE(1);
        if (kt + 2 < 16) WRITE_A(0);
        __syncthreads();
    }

    // ---- epilogue: nontemporal float4 stores (lane holds 4 consecutive n)
    float* og = out + (size_t)(mt * 64) * 4096 + g * 512 + nt * 256 + w * 64;
#pragma unroll
    for (int mi = 0; mi < 4; ++mi)
#pragma unroll
        for (int ni = 0; ni < 4; ++ni)
            __builtin_nontemporal_store(
                acc[mi][ni],
                (fv4*)(og + (size_t)(mi * 16 + lr) * 4096 + ni * 16 + lg * 4));

#undef ISSUE_A
#undef ISSUE_B
#undef WRITE_A
#undef COMPUTE
}

// Safety net if ws is too small for the packed bf16 blocks (4 MiB).
__global__ void bl_fallback(const float* __restrict__ x,
                            const float* __restrict__ blocks,
                            float* __restrict__ out) {
    const int o = blockIdx.x * 256 + threadIdx.x;
    const int col = o & 4095;
    const int row = o >> 12;
    const int g = col >> 9;
    const int n = col & 511;
    const float* xr = x + (size_t)row * 4096 + g * 512;
    const float* wp = blocks + (size_t)g * 512 * 512 + n;
    float s = 0.f;
    for (int m = 0; m < 512; ++m) s += xr[m] * wp[(size_t)m * 512];
    out[o] = s;
}

extern "C" void kernel_launch(void* const* d_in, const int* in_sizes, int n_in,
                              void* d_out, int out_size, void* d_ws, size_t ws_size,
                              hipStream_t stream) {
    const float* x      = (const float*)d_in[0];
    const float* blocks = (const float*)d_in[1];
    float* out          = (float*)d_out;

    const size_t need = (size_t)8 * 16 * 2048 * 16;   // 4 MiB packed B
    if (ws_size >= need) {
        unsigned short* bTgl = (unsigned short*)d_ws;
        bl_pack<<<dim3(8, 8, 8), 256, 0, stream>>>(blocks, bTgl);
        bl_gemm<<<2048, 256, 0, stream>>>(x, bTgl, out);
    } else {
        bl_fallback<<<(8192 * 4096) / 256, 256, 0, stream>>>(x, blocks, out);
    }
}